// Round 11
// baseline (578.032 us; speedup 1.0000x reference)
//
#include <hip/hip_runtime.h>
#include <hip/hip_bf16.h>
#include <hip/hip_cooperative_groups.h>

namespace cg = cooperative_groups;

#define BB 4
#define NN 400
#define DD 100
#define SS 512
#define LPAD 136
#define GRID 256

typedef __attribute__((ext_vector_type(8))) short bf16x8;
typedef __attribute__((ext_vector_type(4))) float f32x4;

__device__ __forceinline__ float prelu_f(float v, float a) { return v >= 0.f ? v : a * v; }

__device__ __forceinline__ unsigned short f2bf(float x) {
    union { __hip_bfloat16 h; unsigned short u; } c;
    c.h = __float2bfloat16(x);   // RNE
    return c.u;
}
__device__ __forceinline__ float bf2f(unsigned short u) {
    return __uint_as_float(((unsigned)u) << 16);
}

__device__ __forceinline__ bf16x8 ldfrag(const unsigned short* rowp, int grp) {
    ushort4 lo = *(const ushort4*)(rowp + grp * 4);
    ushort4 hi = *(const ushort4*)(rowp + grp * 4 + 16);
    bf16x8 r = {(short)lo.x, (short)lo.y, (short)lo.z, (short)lo.w,
                (short)hi.x, (short)hi.y, (short)hi.z, (short)hi.w};
    return r;
}

struct KP {
    const float *x, *G, *Am, *Wgf, *bgf, *agf, *Wg, *bg, *W4a, *b4a, *a4a,
                *W4b, *b4b, *a4b, *W5, *b5, *a5;
    float* out;
    float* ws;
};

// ws layout (float offsets)
#define OFS_G1  0          // 51200
#define OFS_AX  51200      // 204800
#define OFS_SC  256000     // 1048576 (scores, then Bm)
#define OFS_SQ  1304576    // 2048
#define OFS_DH  1306624    // 2048
#define OFS_PW  1308672    // 204800
#define OFS_T1  1513472    // 204800
#define OFS_GX  1718272    // 204800
#define OFS_H1  1923072    // 160000
#define OFS_H2  2083072    // 204800
#define OFS_DV  2287872    // 819200
#define OFS_TMP 3107072    // 160000
#define OFS_PB  3267072    // 1048576 ushorts

#define SMEM_BYTES (64 * LPAD * 2 * 2)   // 34816

// =====================================================================
// One 64x64 output tile, full-K serial, bf16 MFMA (round-9-verified frag
// scheme).  aBf/bBf: operand is bf16 (lda in ushorts).  transB=1: B is
// [n][k]; 0: [k][n] (fp32 only).  EP: 0 plain | 1 prelu(v+bias[n],*al)
// | 2 v*rv[i] | 3 relu(rv[i]*v+bias[n]) | 4 prelu(v+bias[n],*al)+res
// | 5 pdist w/ mirror (call only for i0<=n0).
// =====================================================================
__device__ void mm_tile(char* smemraw,
                        const void* Ap, int aBf, int lda,
                        const void* Bp, int bBf, int ldb, int transB,
                        int i0, int n0, int M, int N, int K,
                        float* C, int ldc, int EP,
                        const float* bias, const float* alphaP,
                        const float* rv, const float* res, int resLd)
{
    unsigned short (*sa)[LPAD] = (unsigned short(*)[LPAD])smemraw;
    unsigned short (*sb)[LPAD] = (unsigned short(*)[LPAD])(smemraw + 64 * LPAD * 2);
    int tid = threadIdx.x;
    int lane = tid & 63, wave = tid >> 6;
    int r16 = lane & 15, grp = (lane >> 4) & 3;
    int wr = wave >> 1, wc = wave & 1;

    f32x4 acc[2][2];
#pragma unroll
    for (int fm = 0; fm < 2; ++fm)
#pragma unroll
        for (int fn = 0; fn < 2; ++fn)
            acc[fm][fn] = (f32x4){0.f, 0.f, 0.f, 0.f};

    __syncthreads();                       // guard smem reuse
    for (int kt = 0; kt < K; kt += 128) {
        // ---- stage A
        if (aBf) {
            const unsigned short* Ab = (const unsigned short*)Ap;
#pragma unroll
            for (int it = 0; it < 8; ++it) {
                int idx = tid + it * 256;
                int row = idx >> 5, kq = (idx & 31) * 4;
                ushort4 u = {0, 0, 0, 0};
                if (i0 + row < M && kt + kq + 4 <= K)
                    u = *(const ushort4*)&Ab[(size_t)(i0 + row) * lda + kt + kq];
                *(ushort4*)&sa[row][kq] = u;
            }
        } else {
            const float* Ab = (const float*)Ap;
#pragma unroll
            for (int it = 0; it < 8; ++it) {
                int idx = tid + it * 256;
                int row = idx >> 5, kq = (idx & 31) * 4;
                float4 v = make_float4(0.f, 0.f, 0.f, 0.f);
                if (i0 + row < M && kt + kq + 4 <= K)
                    v = *(const float4*)&Ab[(size_t)(i0 + row) * lda + kt + kq];
                ushort4 u;
                u.x = f2bf(v.x); u.y = f2bf(v.y); u.z = f2bf(v.z); u.w = f2bf(v.w);
                *(ushort4*)&sa[row][kq] = u;
            }
        }
        // ---- stage B
        if (transB) {
            if (bBf) {
                const unsigned short* Bb = (const unsigned short*)Bp;
#pragma unroll
                for (int it = 0; it < 8; ++it) {
                    int idx = tid + it * 256;
                    int row = idx >> 5, kq = (idx & 31) * 4;
                    ushort4 u = {0, 0, 0, 0};
                    if (n0 + row < N && kt + kq + 4 <= K)
                        u = *(const ushort4*)&Bb[(size_t)(n0 + row) * ldb + kt + kq];
                    *(ushort4*)&sb[row][kq] = u;
                }
            } else {
                const float* Bb = (const float*)Bp;
#pragma unroll
                for (int it = 0; it < 8; ++it) {
                    int idx = tid + it * 256;
                    int row = idx >> 5, kq = (idx & 31) * 4;
                    float4 v = make_float4(0.f, 0.f, 0.f, 0.f);
                    if (n0 + row < N && kt + kq + 4 <= K)
                        v = *(const float4*)&Bb[(size_t)(n0 + row) * ldb + kt + kq];
                    ushort4 u;
                    u.x = f2bf(v.x); u.y = f2bf(v.y); u.z = f2bf(v.z); u.w = f2bf(v.w);
                    *(ushort4*)&sb[row][kq] = u;
                }
            }
        } else {
            const float* Bb = (const float*)Bp;
#pragma unroll
            for (int it = 0; it < 8; ++it) {
                int idx = tid + it * 256;
                int kk = idx >> 4;           // 0..127
                int nq = (idx & 15) * 4;     // 0..60
                float4 v = make_float4(0.f, 0.f, 0.f, 0.f);
                if (kt + kk < K && n0 + nq + 4 <= N)
                    v = *(const float4*)&Bb[(size_t)(kt + kk) * ldb + n0 + nq];
                sb[nq + 0][kk] = f2bf(v.x);
                sb[nq + 1][kk] = f2bf(v.y);
                sb[nq + 2][kk] = f2bf(v.z);
                sb[nq + 3][kk] = f2bf(v.w);
            }
        }
        __syncthreads();
#pragma unroll
        for (int ks = 0; ks < 4; ++ks) {
            bf16x8 a0 = ldfrag(&sa[wr * 32 + r16][ks * 32], grp);
            bf16x8 a1 = ldfrag(&sa[wr * 32 + 16 + r16][ks * 32], grp);
            bf16x8 b0 = ldfrag(&sb[wc * 32 + r16][ks * 32], grp);
            bf16x8 b1 = ldfrag(&sb[wc * 32 + 16 + r16][ks * 32], grp);
            acc[0][0] = __builtin_amdgcn_mfma_f32_16x16x32_bf16(a0, b0, acc[0][0], 0, 0, 0);
            acc[0][1] = __builtin_amdgcn_mfma_f32_16x16x32_bf16(a0, b1, acc[0][1], 0, 0, 0);
            acc[1][0] = __builtin_amdgcn_mfma_f32_16x16x32_bf16(a1, b0, acc[1][0], 0, 0, 0);
            acc[1][1] = __builtin_amdgcn_mfma_f32_16x16x32_bf16(a1, b1, acc[1][1], 0, 0, 0);
        }
        __syncthreads();
    }

    float al = alphaP ? *alphaP : 0.f;
#pragma unroll
    for (int fm = 0; fm < 2; ++fm)
#pragma unroll
        for (int fn = 0; fn < 2; ++fn)
#pragma unroll
            for (int reg = 0; reg < 4; ++reg) {
                int i = i0 + wr * 32 + fm * 16 + grp * 4 + reg;
                int n = n0 + wc * 32 + fn * 16 + r16;
                if (i >= M || n >= N) continue;
                float v = acc[fm][fn][reg];
                if (EP == 1) v = prelu_f(v + bias[n], al);
                else if (EP == 2) v *= rv[i];
                else if (EP == 3) { float t = rv[i] * v + bias[n]; v = t > 0.f ? t : 0.f; }
                else if (EP == 4) v = prelu_f(v + bias[n], al) + res[(size_t)i * resLd + n];
                else if (EP == 5) {
                    float d2 = rv[i] + rv[n] - 2.f * v;
                    v = (i == n) ? 1.f : sqrtf(fmaxf(d2, 0.f));
                }
                C[(size_t)i * ldc + n] = v;
                if (EP == 5) C[(size_t)n * ldc + i] = v;   // mirror (same value; diag benign)
            }
}

// ---------------- phases (each uses blockIdx.x/gridDim.x) ----------------

__device__ void phase_pre(const KP& p, char* sm) {   // G1 (16) + Ax (64) + h1 (56)
    float* G1 = p.ws + OFS_G1;
    float* Ax = p.ws + OFS_AX;
    float* h1 = p.ws + OFS_H1;
    for (int t = blockIdx.x; t < 136; t += gridDim.x) {
        if (t < 16) {
            int it = t >> 1, nt = t & 1;
            mm_tile(sm, p.G, 0, NN, p.Wgf, 0, NN, 1, it * 64, nt * 64, SS, DD, NN,
                    G1, DD, 1, p.bgf, p.agf, nullptr, nullptr, 0);
        } else if (t < 80) {
            int u = t - 16, b = u >> 4, r = u & 15, it = r >> 1, nt = r & 1;
            mm_tile(sm, p.Am, 0, NN, p.x + (size_t)b * NN * DD, 0, DD, 0,
                    it * 64, nt * 64, SS, DD, NN,
                    Ax + (size_t)b * SS * DD, DD, 0, nullptr, nullptr, nullptr, nullptr, 0);
        } else {
            int u = t - 80, b = u / 14, r = u % 14, it = r >> 1, nt = r & 1;
            mm_tile(sm, p.x + (size_t)b * NN * DD, 0, DD, p.W4a, 0, 2 * DD, 1,
                    it * 64, nt * 64, NN, DD, DD,
                    h1 + (size_t)b * NN * DD, DD, 0, nullptr, nullptr, nullptr, nullptr, 0);
        }
    }
}

__device__ void phase_scores(const KP& p, char* sm) {   // 256 tiles
    float* G1 = p.ws + OFS_G1;
    float* Ax = p.ws + OFS_AX;
    float* sc = p.ws + OFS_SC;
    for (int t = blockIdx.x; t < 256; t += gridDim.x) {
        int b = t >> 6, r = t & 63, it = r >> 3, nt = r & 7;
        mm_tile(sm, G1, 0, DD, Ax + (size_t)b * SS * DD, 0, DD, 1,
                it * 64, nt * 64, SS, SS, DD,
                sc + (size_t)b * SS * SS, SS, 0, nullptr, nullptr, nullptr, nullptr, 0);
    }
}

__device__ void phase_softmax(const KP& p, char* sm) {   // 2048 rows / 256 blocks
    float* sc = p.ws + OFS_SC;
    float* sq = p.ws + OFS_SQ;
    unsigned short* Pb = (unsigned short*)(p.ws + OFS_PB);
    float* red = (float*)sm;
    int tid = threadIdx.x, lane = tid & 63, wave = tid >> 6;
    __syncthreads();
    for (int r8 = 0; r8 < 8; ++r8) {
        int row = blockIdx.x * 8 + r8;
        const float* srow = sc + (size_t)row * SS;
        float v0 = srow[tid], v1 = srow[tid + 256];
        float m = fmaxf(v0, v1);
        for (int off = 32; off; off >>= 1) m = fmaxf(m, __shfl_xor(m, off, 64));
        if (lane == 0) red[wave] = m;
        __syncthreads();
        m = fmaxf(fmaxf(red[0], red[1]), fmaxf(red[2], red[3]));
        __syncthreads();
        float e0 = expf(v0 - m), e1 = expf(v1 - m);
        float s = e0 + e1;
        for (int off = 32; off; off >>= 1) s += __shfl_xor(s, off, 64);
        if (lane == 0) red[wave] = s;
        __syncthreads();
        s = red[0] + red[1] + red[2] + red[3];
        __syncthreads();
        float inv = 1.f / s;
        unsigned short u0 = f2bf(e0 * inv), u1 = f2bf(e1 * inv);
        Pb[(size_t)row * SS + tid] = u0;
        Pb[(size_t)row * SS + tid + 256] = u1;
        float p0 = bf2f(u0), p1 = bf2f(u1);
        float q = p0 * p0 + p1 * p1;
        for (int off = 32; off; off >>= 1) q += __shfl_xor(q, off, 64);
        if (lane == 0) red[wave] = q;
        __syncthreads();
        if (tid == 0) sq[row] = red[0] + red[1] + red[2] + red[3];
        __syncthreads();
    }
}

__device__ void phase_gram(const KP& p, char* sm) {   // pdist (144) + PW (64)
    float* Bm = p.ws + OFS_SC;
    float* sq = p.ws + OFS_SQ;
    float* PW = p.ws + OFS_PW;
    unsigned short* Pb = (unsigned short*)(p.ws + OFS_PB);
    for (int t = blockIdx.x; t < 208; t += gridDim.x) {
        if (t < 144) {
            int b = t / 36, r = t % 36, it = 0, nt = 0;
            for (it = 0; it < 8; ++it) { int cnt = 8 - it; if (r < cnt) { nt = it + r; break; } r -= cnt; }
            mm_tile(sm, Pb + (size_t)b * SS * SS, 1, SS, Pb + (size_t)b * SS * SS, 1, SS, 1,
                    it * 64, nt * 64, SS, SS, SS,
                    Bm + (size_t)b * SS * SS, SS, 5, nullptr, nullptr, sq + (size_t)b * SS, nullptr, 0);
        } else {
            int u = t - 144, b = u >> 4, r = u & 15, it = r >> 1, nt = r & 1;
            mm_tile(sm, Pb + (size_t)b * SS * SS, 1, SS, p.Wg, 0, SS, 1,
                    it * 64, nt * 64, SS, DD, SS,
                    PW + (size_t)b * SS * DD, DD, 0, nullptr, nullptr, nullptr, nullptr, 0);
        }
    }
}

__device__ void phase_dh(const KP& p, char* sm) {   // 2048 rows / 256 blocks
    float* Bm = p.ws + OFS_SC;
    float* dh = p.ws + OFS_DH;
    float* red = (float*)sm;
    int tid = threadIdx.x, lane = tid & 63, wave = tid >> 6;
    __syncthreads();
    for (int r8 = 0; r8 < 8; ++r8) {
        int row = blockIdx.x * 8 + r8;
        const float* brow = Bm + (size_t)row * SS;
        float v = brow[tid] + brow[tid + 256];
        for (int off = 32; off; off >>= 1) v += __shfl_xor(v, off, 64);
        if (lane == 0) red[wave] = v;
        __syncthreads();
        if (tid == 0) dh[row] = rsqrtf(red[0] + red[1] + red[2] + red[3]);
        __syncthreads();
    }
}

__device__ void phase_t1(const KP& p, char* sm) {   // 64 tiles
    float* Bm = p.ws + OFS_SC;
    float* PW = p.ws + OFS_PW;
    float* T1 = p.ws + OFS_T1;
    float* dh = p.ws + OFS_DH;
    for (int t = blockIdx.x; t < 64; t += gridDim.x) {
        int b = t >> 4, r = t & 15, it = r >> 1, nt = r & 1;
        mm_tile(sm, Bm + (size_t)b * SS * SS, 0, SS, PW + (size_t)b * SS * DD, 0, DD, 0,
                it * 64, nt * 64, SS, DD, SS,
                T1 + (size_t)b * SS * DD, DD, 2, nullptr, nullptr, dh + (size_t)b * SS, nullptr, 0);
    }
}

__device__ void phase_gx(const KP& p, char* sm) {   // 64 tiles
    float* Bm = p.ws + OFS_SC;
    float* T1 = p.ws + OFS_T1;
    float* gx = p.ws + OFS_GX;
    float* dh = p.ws + OFS_DH;
    for (int t = blockIdx.x; t < 64; t += gridDim.x) {
        int b = t >> 4, r = t & 15, it = r >> 1, nt = r & 1;
        mm_tile(sm, Bm + (size_t)b * SS * SS, 0, SS, T1 + (size_t)b * SS * DD, 0, DD, 0,
                it * 64, nt * 64, SS, DD, SS,
                gx + (size_t)b * SS * DD, DD, 3, p.bg, nullptr, dh + (size_t)b * SS, nullptr, 0);
    }
}

__device__ void phase_h2(const KP& p, char* sm) {   // 64 tiles
    float* gx = p.ws + OFS_GX;
    float* h2 = p.ws + OFS_H2;
    for (int t = blockIdx.x; t < 64; t += gridDim.x) {
        int b = t >> 4, r = t & 15, it = r >> 1, nt = r & 1;
        mm_tile(sm, gx + (size_t)b * SS * DD, 0, DD, p.W4a + DD, 0, 2 * DD, 1,
                it * 64, nt * 64, SS, DD, DD,
                h2 + (size_t)b * SS * DD, DD, 0, nullptr, nullptr, nullptr, nullptr, 0);
    }
}

struct DivS { float sh[8][104]; float sw[104]; float L[8][400]; };

__device__ void phase_div(const KP& p, char* sm) {   // 256 blocks = 64 s-grp x 4 b
    float* h1 = p.ws + OFS_H1;
    float* h2 = p.ws + OFS_H2;
    float* dv = p.ws + OFS_DV;
    DivS* sd = (DivS*)sm;
    int b = blockIdx.x >> 6;
    int s0 = (blockIdx.x & 63) * 8;
    int tid = threadIdx.x;
    __syncthreads();
    for (int idx = tid; idx < 800; idx += 256) {
        int s = idx / 100, d = idx - 100 * s;
        sd->sh[s][d] = h2[((size_t)(b * SS + s0 + s)) * DD + d] + p.b4a[d];
    }
    if (tid < 100) sd->sw[tid] = p.W4b[tid];
    __syncthreads();

    float a4a = *p.a4a, a4b = *p.a4b, b4b = *p.b4b;

    for (int n = tid; n < NN; n += 256) {
        const float* h1r = &h1[((size_t)b * NN + n) * DD];
        float accs[8] = {0.f, 0.f, 0.f, 0.f, 0.f, 0.f, 0.f, 0.f};
        for (int j = 0; j < DD; j += 4) {
            float4 hv = *(const float4*)&h1r[j];
            float4 wv = *(const float4*)&sd->sw[j];
#pragma unroll
            for (int s = 0; s < 8; ++s) {
                float4 cv = *(const float4*)&sd->sh[s][j];
                float x0 = hv.x + cv.x; x0 = x0 > 0.f ? x0 : a4a * x0;
                float x1 = hv.y + cv.y; x1 = x1 > 0.f ? x1 : a4a * x1;
                float x2 = hv.z + cv.z; x2 = x2 > 0.f ? x2 : a4a * x2;
                float x3 = hv.w + cv.w; x3 = x3 > 0.f ? x3 : a4a * x3;
                accs[s] += x0 * wv.x + x1 * wv.y + x2 * wv.z + x3 * wv.w;
            }
        }
#pragma unroll
        for (int s = 0; s < 8; ++s) sd->L[s][n] = prelu_f(accs[s] + b4b, a4b);
    }
    __syncthreads();

    int w = tid >> 6, lane = tid & 63;
    for (int si = w; si < 8; si += 4) {
        float m = -INFINITY;
        for (int n = lane; n < NN; n += 64) m = fmaxf(m, sd->L[si][n]);
        for (int off = 32; off; off >>= 1) m = fmaxf(m, __shfl_xor(m, off, 64));
        float ss = 0.f;
        for (int n = lane; n < NN; n += 64) {
            float e = expf(sd->L[si][n] - m);
            sd->L[si][n] = e;
            ss += e;
        }
        for (int off = 32; off; off >>= 1) ss += __shfl_xor(ss, off, 64);
        float inv = 1.f / ss;
        for (int n = lane; n < NN; n += 64)
            dv[((size_t)b * NN + n) * SS + s0 + si] = sd->L[si][n] * inv;
    }
    __syncthreads();
}

__device__ void phase_tmp(const KP& p, char* sm) {   // 56 tiles
    float* dv  = p.ws + OFS_DV;
    float* gx  = p.ws + OFS_GX;
    float* tmp = p.ws + OFS_TMP;
    for (int t = blockIdx.x; t < 56; t += gridDim.x) {
        int b = t / 14, r = t % 14, it = r >> 1, nt = r & 1;
        mm_tile(sm, dv + (size_t)b * NN * SS, 0, SS, gx + (size_t)b * SS * DD, 0, DD, 0,
                it * 64, nt * 64, NN, DD, SS,
                tmp + (size_t)b * NN * DD, DD, 0, nullptr, nullptr, nullptr, nullptr, 0);
    }
}

__device__ void phase_out(const KP& p, char* sm) {   // 56 tiles
    float* tmp = p.ws + OFS_TMP;
    for (int t = blockIdx.x; t < 56; t += gridDim.x) {
        int b = t / 14, r = t % 14, it = r >> 1, nt = r & 1;
        mm_tile(sm, tmp + (size_t)b * NN * DD, 0, DD, p.W5, 0, DD, 1,
                it * 64, nt * 64, NN, DD, DD,
                p.out + (size_t)b * NN * DD, DD, 4, p.b5, p.a5,
                nullptr, p.x + (size_t)b * NN * DD, DD);
    }
}

// ---------------- persistent cooperative kernel ----------------
__global__ __launch_bounds__(256)
void persist(KP p) {
    __shared__ __align__(16) char sm[SMEM_BYTES];
    cg::grid_group g = cg::this_grid();
    phase_pre(p, sm);      g.sync();
    phase_scores(p, sm);   g.sync();
    phase_softmax(p, sm);  g.sync();
    phase_gram(p, sm);     g.sync();
    phase_dh(p, sm);       g.sync();
    phase_t1(p, sm);       g.sync();
    phase_gx(p, sm);       g.sync();
    phase_h2(p, sm);       g.sync();
    phase_div(p, sm);      g.sync();
    phase_tmp(p, sm);      g.sync();
    phase_out(p, sm);
}

// ---------------- fallback: same phases as separate kernels ----------------
#define PHASE_KERNEL(name, fn) \
    __global__ __launch_bounds__(256) void name(KP p) { \
        __shared__ __align__(16) char sm[SMEM_BYTES]; fn(p, sm); }
PHASE_KERNEL(kPre, phase_pre)
PHASE_KERNEL(kScores, phase_scores)
PHASE_KERNEL(kSoftmax, phase_softmax)
PHASE_KERNEL(kGram, phase_gram)
PHASE_KERNEL(kDh, phase_dh)
PHASE_KERNEL(kT1, phase_t1)
PHASE_KERNEL(kGx, phase_gx)
PHASE_KERNEL(kH2, phase_h2)
PHASE_KERNEL(kDiv, phase_div)
PHASE_KERNEL(kTmp, phase_tmp)
PHASE_KERNEL(kOut, phase_out)

extern "C" void kernel_launch(void* const* d_in, const int* in_sizes, int n_in,
                              void* d_out, int out_size, void* d_ws, size_t ws_size,
                              hipStream_t stream) {
    KP kp;
    kp.x   = (const float*)d_in[0];
    kp.G   = (const float*)d_in[1];
    kp.Am  = (const float*)d_in[2];
    kp.Wgf = (const float*)d_in[3];
    kp.bgf = (const float*)d_in[4];
    kp.agf = (const float*)d_in[5];
    kp.Wg  = (const float*)d_in[6];
    kp.bg  = (const float*)d_in[7];
    kp.W4a = (const float*)d_in[8];
    kp.b4a = (const float*)d_in[9];
    kp.a4a = (const float*)d_in[10];
    kp.W4b = (const float*)d_in[11];
    kp.b4b = (const float*)d_in[12];
    kp.a4b = (const float*)d_in[13];
    kp.W5  = (const float*)d_in[14];
    kp.b5  = (const float*)d_in[15];
    kp.a5  = (const float*)d_in[16];
    kp.out = (float*)d_out;
    kp.ws  = (float*)d_ws;

    void* args[] = { (void*)&kp };
    hipError_t err = hipLaunchCooperativeKernel((const void*)persist,
                                                dim3(GRID), dim3(256), args, 0, stream);
    if (err != hipSuccess) {
        (void)hipGetLastError();   // clear, fall back to plain phase kernels
        kPre<<<GRID, 256, 0, stream>>>(kp);
        kScores<<<GRID, 256, 0, stream>>>(kp);
        kSoftmax<<<GRID, 256, 0, stream>>>(kp);
        kGram<<<GRID, 256, 0, stream>>>(kp);
        kDh<<<GRID, 256, 0, stream>>>(kp);
        kT1<<<GRID, 256, 0, stream>>>(kp);
        kGx<<<GRID, 256, 0, stream>>>(kp);
        kH2<<<GRID, 256, 0, stream>>>(kp);
        kDiv<<<GRID, 256, 0, stream>>>(kp);
        kTmp<<<GRID, 256, 0, stream>>>(kp);
        kOut<<<GRID, 256, 0, stream>>>(kp);
    }
}

// Round 13
// 276.549 us; speedup vs baseline: 2.0902x; 2.0902x over previous
//
#include <hip/hip_runtime.h>
#include <hip/hip_bf16.h>

#define BB 4
#define NN 400
#define DD 100
#define SS 512

typedef __attribute__((ext_vector_type(8))) short bf16x8;
typedef __attribute__((ext_vector_type(4))) float f32x4;

__device__ __forceinline__ float prelu_f(float v, float a) { return v >= 0.f ? v : a * v; }

__device__ __forceinline__ unsigned short f2bf(float x) {
    union { __hip_bfloat16 h; unsigned short u; } c;
    c.h = __float2bfloat16(x);   // RNE
    return c.u;
}
__device__ __forceinline__ float bf2f(unsigned short u) {
    return __uint_as_float(((unsigned)u) << 16);
}

__device__ __forceinline__ bf16x8 ldfrag(const unsigned short* rowp, int grp) {
    ushort4 lo = *(const ushort4*)(rowp + grp * 4);
    ushort4 hi = *(const ushort4*)(rowp + grp * 4 + 16);
    bf16x8 r = {(short)lo.x, (short)lo.y, (short)lo.z, (short)lo.w,
                (short)hi.x, (short)hi.y, (short)hi.z, (short)hi.w};
    return r;
}

#define LPAD 136   // row stride (ushorts): 68 dwords == 4 mod 32 -> <=2-way on frag reads

// =====================================================================
// MFMA bf16 GEMM, 256 thr (4 waves 2x2), tile 64x64, K-step 128.
// flags: bit0 = A is bf16 (lda/sA in ushorts); bit1 = B is bf16
// (transB=1 only).  A2p/B2p: optional second fp32 pointer summed at
// staging (folds a 2-way split-K reduce into this GEMM's load).
// nsplit>1: raw partials to C[(b*nsplit+split)*M*N]  (EP==5 still
// triggers the triangular block skip first — partials exist only for
// i0<=n0 tiles, which covers every (i<=n) pair).
// nsplit==1 epilogues: 0 none | 4 prelu(v+bias[n],*alpha)+res | 5 pdist
// (triangular + mirror writes).
// =====================================================================
__global__ __launch_bounds__(256)
void mmfa(const void* __restrict__ Ap, const void* __restrict__ A2p, int lda, int sA,
          const void* __restrict__ Bp, const void* __restrict__ B2p, int ldb, int sB,
          int transB, int flags,
          float* __restrict__ C, int sC, int M, int N, int K,
          int nsplit, int kchunk, int EP,
          const float* __restrict__ bias, const float* __restrict__ alpha,
          const float* __restrict__ rv, int rvStride,
          const float* __restrict__ res, int sRes)
{
    int zz = blockIdx.z;
    int b = zz / nsplit, split = zz - b * nsplit;
    int kbeg = split * kchunk, kend = min(K, kbeg + kchunk);
    int i0 = blockIdx.x * 64, n0 = blockIdx.y * 64;
    if (EP == 5 && i0 > n0) return;          // symmetric: lower half from kbm/mirror

    int tid = threadIdx.x;
    int lane = tid & 63, wave = tid >> 6;
    int r16 = lane & 15, grp = (lane >> 4) & 3;
    int wr = wave >> 1, wc = wave & 1;       // 2x2 wave grid

    __shared__ unsigned short sa[64][LPAD];
    __shared__ unsigned short sb[64][LPAD];

    f32x4 acc[2][2];
#pragma unroll
    for (int fm = 0; fm < 2; ++fm)
#pragma unroll
        for (int fn = 0; fn < 2; ++fn)
            acc[fm][fn] = (f32x4){0.f, 0.f, 0.f, 0.f};

    for (int kt = kbeg; kt < kend; kt += 128) {
        // ---- stage A (64 rows x 128 k)
        if (flags & 1) {
            const unsigned short* Ab = (const unsigned short*)Ap + (size_t)b * sA;
#pragma unroll
            for (int it = 0; it < 8; ++it) {
                int idx = tid + it * 256;
                int row = idx >> 5, kq = (idx & 31) * 4;
                ushort4 u = {0, 0, 0, 0};
                if (i0 + row < M && kt + kq + 4 <= kend)
                    u = *(const ushort4*)&Ab[(size_t)(i0 + row) * lda + kt + kq];
                *(ushort4*)&sa[row][kq] = u;
            }
        } else {
            const float* Ab  = (const float*)Ap + (size_t)b * sA;
            const float* Ab2 = A2p ? (const float*)A2p + (size_t)b * sA : nullptr;
#pragma unroll
            for (int it = 0; it < 8; ++it) {
                int idx = tid + it * 256;
                int row = idx >> 5, kq = (idx & 31) * 4;
                float4 v = make_float4(0.f, 0.f, 0.f, 0.f);
                if (i0 + row < M && kt + kq + 4 <= kend) {
                    v = *(const float4*)&Ab[(size_t)(i0 + row) * lda + kt + kq];
                    if (Ab2) {
                        float4 w = *(const float4*)&Ab2[(size_t)(i0 + row) * lda + kt + kq];
                        v.x += w.x; v.y += w.y; v.z += w.z; v.w += w.w;
                    }
                }
                ushort4 u;
                u.x = f2bf(v.x); u.y = f2bf(v.y); u.z = f2bf(v.z); u.w = f2bf(v.w);
                *(ushort4*)&sa[row][kq] = u;
            }
        }
        // ---- stage B
        if (transB) {
            if (flags & 2) {
                const unsigned short* Bb = (const unsigned short*)Bp + (size_t)b * sB;
#pragma unroll
                for (int it = 0; it < 8; ++it) {
                    int idx = tid + it * 256;
                    int row = idx >> 5, kq = (idx & 31) * 4;
                    ushort4 u = {0, 0, 0, 0};
                    if (n0 + row < N && kt + kq + 4 <= kend)
                        u = *(const ushort4*)&Bb[(size_t)(n0 + row) * ldb + kt + kq];
                    *(ushort4*)&sb[row][kq] = u;
                }
            } else {
                const float* Bb  = (const float*)Bp + (size_t)b * sB;
                const float* Bb2 = B2p ? (const float*)B2p + (size_t)b * sB : nullptr;
#pragma unroll
                for (int it = 0; it < 8; ++it) {
                    int idx = tid + it * 256;
                    int row = idx >> 5, kq = (idx & 31) * 4;
                    float4 v = make_float4(0.f, 0.f, 0.f, 0.f);
                    if (n0 + row < N && kt + kq + 4 <= kend) {
                        v = *(const float4*)&Bb[(size_t)(n0 + row) * ldb + kt + kq];
                        if (Bb2) {
                            float4 w = *(const float4*)&Bb2[(size_t)(n0 + row) * ldb + kt + kq];
                            v.x += w.x; v.y += w.y; v.z += w.z; v.w += w.w;
                        }
                    }
                    ushort4 u;
                    u.x = f2bf(v.x); u.y = f2bf(v.y); u.z = f2bf(v.z); u.w = f2bf(v.w);
                    *(ushort4*)&sb[row][kq] = u;
                }
            }
        } else {
            const float* Bb  = (const float*)Bp + (size_t)b * sB;
            const float* Bb2 = B2p ? (const float*)B2p + (size_t)b * sB : nullptr;
#pragma unroll
            for (int it = 0; it < 8; ++it) {
                int idx = tid + it * 256;
                int kk = idx >> 4;           // 0..127
                int nq = (idx & 15) * 4;     // 0..60
                float4 v = make_float4(0.f, 0.f, 0.f, 0.f);
                if (kt + kk < kend && n0 + nq + 4 <= N) {
                    v = *(const float4*)&Bb[(size_t)(kt + kk) * ldb + n0 + nq];
                    if (Bb2) {
                        float4 w = *(const float4*)&Bb2[(size_t)(kt + kk) * ldb + n0 + nq];
                        v.x += w.x; v.y += w.y; v.z += w.z; v.w += w.w;
                    }
                }
                sb[nq + 0][kk] = f2bf(v.x);
                sb[nq + 1][kk] = f2bf(v.y);
                sb[nq + 2][kk] = f2bf(v.z);
                sb[nq + 3][kk] = f2bf(v.w);
            }
        }
        __syncthreads();

#pragma unroll
        for (int ks = 0; ks < 4; ++ks) {     // 4 x K=32 sub-windows
            bf16x8 a0 = ldfrag(&sa[wr * 32 + r16][ks * 32], grp);
            bf16x8 a1 = ldfrag(&sa[wr * 32 + 16 + r16][ks * 32], grp);
            bf16x8 b0 = ldfrag(&sb[wc * 32 + r16][ks * 32], grp);
            bf16x8 b1 = ldfrag(&sb[wc * 32 + 16 + r16][ks * 32], grp);
            acc[0][0] = __builtin_amdgcn_mfma_f32_16x16x32_bf16(a0, b0, acc[0][0], 0, 0, 0);
            acc[0][1] = __builtin_amdgcn_mfma_f32_16x16x32_bf16(a0, b1, acc[0][1], 0, 0, 0);
            acc[1][0] = __builtin_amdgcn_mfma_f32_16x16x32_bf16(a1, b0, acc[1][0], 0, 0, 0);
            acc[1][1] = __builtin_amdgcn_mfma_f32_16x16x32_bf16(a1, b1, acc[1][1], 0, 0, 0);
        }
        __syncthreads();
    }

    // ---- store: i = i0 + wr*32 + fm*16 + grp*4 + reg, n = n0 + wc*32 + fn*16 + r16
    if (nsplit > 1) {
        float* Pp = C + (size_t)(b * nsplit + split) * M * N;
#pragma unroll
        for (int fm = 0; fm < 2; ++fm)
#pragma unroll
            for (int fn = 0; fn < 2; ++fn)
#pragma unroll
                for (int reg = 0; reg < 4; ++reg) {
                    int i = i0 + wr * 32 + fm * 16 + grp * 4 + reg;
                    int n = n0 + wc * 32 + fn * 16 + r16;
                    if (i < M && n < N) Pp[(size_t)i * N + n] = acc[fm][fn][reg];
                }
        return;
    }

    float al = alpha ? *alpha : 0.f;
    const float* rvb = rv ? rv + (size_t)b * rvStride : nullptr;
    float* Cb = C + (size_t)b * sC;
#pragma unroll
    for (int fm = 0; fm < 2; ++fm)
#pragma unroll
        for (int fn = 0; fn < 2; ++fn)
#pragma unroll
            for (int reg = 0; reg < 4; ++reg) {
                int i = i0 + wr * 32 + fm * 16 + grp * 4 + reg;
                int n = n0 + wc * 32 + fn * 16 + r16;
                if (i >= M || n >= N) continue;
                float v = acc[fm][fn][reg];
                if (EP == 4) {
                    v = prelu_f(v + bias[n], al) + res[(size_t)b * sRes + (size_t)i * N + n];
                } else if (EP == 5) {
                    float d2 = rvb[i] + rvb[n] - 2.f * v;
                    v = (i == n) ? 1.f : sqrtf(fmaxf(d2, 0.f));
                }
                Cb[(size_t)i * N + n] = v;
                if (EP == 5) Cb[(size_t)n * N + i] = v;
            }
}

// =====================================================================
// Split-K reduce with epilogue.  One float4 per thread.
// EP: 0 none | 1 prelu(v+bias[n],*alpha) | 2 v*rv[i] | 3 relu(rv[i]*v+bias[n])
// =====================================================================
__global__ __launch_bounds__(256)
void k_reduce(const float* __restrict__ part, int nsplit, float* __restrict__ C, int sC,
              int M, int N, int EP, const float* __restrict__ bias,
              const float* __restrict__ alpha, const float* __restrict__ rv, int rvStride)
{
    int b = blockIdx.y;
    int MN = M * N;
    int flat = (blockIdx.x * 256 + threadIdx.x) * 4;
    if (flat >= MN) return;
    const float* p = part + (size_t)b * nsplit * MN + flat;
    float4 v = *(const float4*)p;
    for (int s = 1; s < nsplit; ++s) {
        float4 w = *(const float4*)(p + (size_t)s * MN);
        v.x += w.x; v.y += w.y; v.z += w.z; v.w += w.w;
    }
    float o[4] = {v.x, v.y, v.z, v.w};
    int i = flat / N, n = flat - i * N;     // N % 4 == 0: float4 never crosses a row
    if (EP == 1) {
        float al = *alpha;
#pragma unroll
        for (int j = 0; j < 4; ++j) o[j] = prelu_f(o[j] + bias[n + j], al);
    } else if (EP == 2) {
        float r = rv[(size_t)b * rvStride + i];
#pragma unroll
        for (int j = 0; j < 4; ++j) o[j] *= r;
    } else if (EP == 3) {
        float r = rv[(size_t)b * rvStride + i];
#pragma unroll
        for (int j = 0; j < 4; ++j) { float t = r * o[j] + bias[n + j]; o[j] = t > 0.f ? t : 0.f; }
    }
    float* co = C + (size_t)b * sC + flat;
    *(float4*)co = make_float4(o[0], o[1], o[2], o[3]);
}

// =====================================================================
// kbm: pdist epilogue over 4 split-K partials of the gram.  Partials
// exist only at [lo][hi] (upper triangle, from the triangular mmfa
// skip); gram is symmetric so (i,n) reads [min][max].  Writes Bm fully
// (coalesced float4 rows).  Bm[i][i] = 1.
// =====================================================================
__global__ __launch_bounds__(256)
void kbm(const float* __restrict__ parts, const float* __restrict__ sq,
         float* __restrict__ Bm)
{
    int b = blockIdx.y;
    int flat = (blockIdx.x * 256 + threadIdx.x) * 4;   // < SS*SS
    int i = flat / SS, n0 = flat - i * SS;
    const float* pb = parts + (size_t)b * 4 * SS * SS;
    const float* sqb = sq + (size_t)b * SS;
    float o[4];
#pragma unroll
    for (int j = 0; j < 4; ++j) {
        int n = n0 + j;
        int lo = min(i, n), hi = max(i, n);
        size_t idx = (size_t)lo * SS + hi;
        float d = pb[idx] + pb[(size_t)SS * SS + idx]
                + pb[2 * (size_t)SS * SS + idx] + pb[3 * (size_t)SS * SS + idx];
        float d2 = sqb[i] + sqb[n] - 2.f * d;
        o[j] = (i == n) ? 1.f : sqrtf(fmaxf(d2, 0.f));
    }
    *(float4*)&Bm[(size_t)b * SS * SS + flat] = make_float4(o[0], o[1], o[2], o[3]);
}

// =====================================================================
// Row softmax over 512 cols -> P as bf16, sq = sum(bf16(p)^2).
// =====================================================================
__global__ __launch_bounds__(512)
void k_softmax_sq(const float* __restrict__ scores, unsigned short* __restrict__ Pb,
                  float* __restrict__ sq)
{
    int row = blockIdx.x;
    int t = threadIdx.x;
    int w = t >> 6, lane = t & 63;
    __shared__ float sm[8];

    float v = scores[(size_t)row * SS + t];
    float m = v;
    for (int off = 32; off; off >>= 1) m = fmaxf(m, __shfl_xor(m, off, 64));
    if (lane == 0) sm[w] = m;
    __syncthreads();
    m = sm[0];
#pragma unroll
    for (int i = 1; i < 8; ++i) m = fmaxf(m, sm[i]);
    __syncthreads();

    float e = expf(v - m);
    float s = e;
    for (int off = 32; off; off >>= 1) s += __shfl_xor(s, off, 64);
    if (lane == 0) sm[w] = s;
    __syncthreads();
    s = 0.f;
#pragma unroll
    for (int i = 0; i < 8; ++i) s += sm[i];
    __syncthreads();

    unsigned short u = f2bf(e / s);
    Pb[(size_t)row * SS + t] = u;
    float pf = bf2f(u);
    float q = pf * pf;
    for (int off = 32; off; off >>= 1) q += __shfl_xor(q, off, 64);
    if (lane == 0) sm[w] = q;
    __syncthreads();
    if (t == 0) {
        float r = 0.f;
#pragma unroll
        for (int i = 0; i < 8; ++i) r += sm[i];
        sq[row] = r;
    }
}

// =====================================================================
// dh[row] = rsqrt(rowsum(Bm))
// =====================================================================
__global__ __launch_bounds__(512)
void k_dh(const float* __restrict__ Bm, float* __restrict__ dh)
{
    int row = blockIdx.x;
    int t = threadIdx.x;
    int w = t >> 6, lane = t & 63;
    __shared__ float sm[8];
    float v = Bm[(size_t)row * SS + t];
    for (int off = 32; off; off >>= 1) v += __shfl_xor(v, off, 64);
    if (lane == 0) sm[w] = v;
    __syncthreads();
    if (t == 0) {
        float r = 0.f;
#pragma unroll
        for (int i = 0; i < 8; ++i) r += sm[i];
        dh[row] = rsqrtf(r);
    }
}

// =====================================================================
// Logits + softmax over n.  block = (b, 8 s-rows), 256 thr.
// div written in (b, n, s) layout.
// =====================================================================
__global__ __launch_bounds__(256)
void k_div8(const float* __restrict__ h1, const float* __restrict__ h2,
            const float* __restrict__ b4a, const float* __restrict__ a4ap,
            const float* __restrict__ W4b, const float* __restrict__ b4bp,
            const float* __restrict__ a4bp, float* __restrict__ divT)
{
    int b = blockIdx.y;
    int s0 = blockIdx.x * 8;
    int tid = threadIdx.x;

    __shared__ float sh[8][104];
    __shared__ float sw[100];
    __shared__ float L[8][400];

    for (int idx = tid; idx < 800; idx += 256) {
        int s = idx / 100, d = idx - 100 * s;
        sh[s][d] = h2[((size_t)(b * SS + s0 + s)) * DD + d] + b4a[d];
    }
    if (tid < 100) sw[tid] = W4b[tid];
    __syncthreads();

    float a4a = *a4ap, a4b = *a4bp, b4b = *b4bp;

    for (int n = tid; n < NN; n += 256) {
        const float* h1r = &h1[((size_t)b * NN + n) * DD];
        float accs[8] = {0.f, 0.f, 0.f, 0.f, 0.f, 0.f, 0.f, 0.f};
        for (int j = 0; j < DD; j += 4) {
            float4 hv = *(const float4*)&h1r[j];
            float4 wv = *(const float4*)&sw[j];
#pragma unroll
            for (int s = 0; s < 8; ++s) {
                float4 cv = *(const float4*)&sh[s][j];
                float x0 = hv.x + cv.x; x0 = x0 > 0.f ? x0 : a4a * x0;
                float x1 = hv.y + cv.y; x1 = x1 > 0.f ? x1 : a4a * x1;
                float x2 = hv.z + cv.z; x2 = x2 > 0.f ? x2 : a4a * x2;
                float x3 = hv.w + cv.w; x3 = x3 > 0.f ? x3 : a4a * x3;
                accs[s] += x0 * wv.x + x1 * wv.y + x2 * wv.z + x3 * wv.w;
            }
        }
#pragma unroll
        for (int s = 0; s < 8; ++s) L[s][n] = prelu_f(accs[s] + b4b, a4b);
    }
    __syncthreads();

    int w = tid >> 6, lane = tid & 63;
    for (int si = w; si < 8; si += 4) {
        float m = -INFINITY;
        for (int n = lane; n < NN; n += 64) m = fmaxf(m, L[si][n]);
        for (int off = 32; off; off >>= 1) m = fmaxf(m, __shfl_xor(m, off, 64));
        float ss = 0.f;
        for (int n = lane; n < NN; n += 64) {
            float e = expf(L[si][n] - m);
            L[si][n] = e;
            ss += e;
        }
        for (int off = 32; off; off >>= 1) ss += __shfl_xor(ss, off, 64);
        float inv = 1.f / ss;
        for (int n = lane; n < NN; n += 64)
            divT[((size_t)b * NN + n) * SS + s0 + si] = L[si][n] * inv;
    }
}

extern "C" void kernel_launch(void* const* d_in, const int* in_sizes, int n_in,
                              void* d_out, int out_size, void* d_ws, size_t ws_size,
                              hipStream_t stream) {
    const float* x   = (const float*)d_in[0];
    const float* G   = (const float*)d_in[1];
    const float* Am  = (const float*)d_in[2];
    const float* Wgf = (const float*)d_in[3];
    const float* bgf = (const float*)d_in[4];
    const float* agf = (const float*)d_in[5];
    const float* Wg  = (const float*)d_in[6];
    const float* bg  = (const float*)d_in[7];
    const float* W4a = (const float*)d_in[8];
    const float* b4a = (const float*)d_in[9];
    const float* a4a = (const float*)d_in[10];
    const float* W4b = (const float*)d_in[11];
    const float* b4b = (const float*)d_in[12];
    const float* a4b = (const float*)d_in[13];
    const float* W5  = (const float*)d_in[14];
    const float* b5  = (const float*)d_in[15];
    const float* a5  = (const float*)d_in[16];
    float* out = (float*)d_out;

    float* ws = (float*)d_ws;
    float* G1   = ws + 0;         // 51200
    float* G1P  = ws + 51200;     // 204800  (4 partials)
    float* AXP  = ws + 256000;    // 409600  (2 x 4b)
    float* SC   = ws + 665600;    // 1048576 (scores fp32)
    float* BM   = ws + 1714176;   // 1048576
    float* SQ   = ws + 2762752;   // 2048
    float* DH   = ws + 2764800;   // 2048
    float* PDP  = ws + 2766848;   // 4194304 (pdist partials 16 x 262144)
    float* PWP  = ws + 6961152;   // 819200  (16 x 51200)
    float* PW   = ws + 7780352;   // 204800
    float* T1P  = ws + 7985152;   // 819200
    float* T1   = ws + 8804352;   // 204800
    float* GXP  = ws + 9009152;   // 819200
    float* GX   = ws + 9828352;   // 204800
    float* H1   = ws + 10033152;  // 160000
    float* H2   = ws + 10193152;  // 204800
    float* DV   = ws + 10397952;  // 819200
    float* TMPP = ws + 11217152;  // 640000  (16 x 40000)
    float* TMP  = ws + 11857152;  // 160000
    unsigned short* PB = (unsigned short*)(ws + 12017152);  // 1048576 ushorts

    // 1-2. G1 = prelu(G @ Wgf^T + bgf)   ns4 (1 kt/block) + reduce EP1
    mmfa<<<dim3(8, 2, 4), 256, 0, stream>>>(G, nullptr, NN, 0, Wgf, nullptr, NN, 0, 1, 0,
        G1P, 0, SS, DD, NN, 4, 100, 0, nullptr, nullptr, nullptr, 0, nullptr, 0);
    k_reduce<<<dim3(50, 1), 256, 0, stream>>>(G1P, 4, G1, SS * DD, SS, DD, 1, bgf, agf, nullptr, 0);
    // 3. Ax partials ns2 (reduce folded into scores' B2p)
    mmfa<<<dim3(8, 2, 2 * BB), 256, 0, stream>>>(Am, nullptr, NN, 0, x, nullptr, DD, NN * DD, 0, 0,
        AXP, 0, SS, DD, NN, 2, 200, 0, nullptr, nullptr, nullptr, 0, nullptr, 0);
    // 4. scores = G1 @ (Ax0+Ax1)^T       256 blocks, 1 kt
    mmfa<<<dim3(8, 8, BB), 256, 0, stream>>>(G1, nullptr, DD, 0,
        AXP, AXP + SS * DD, DD, 2 * SS * DD, 1, 0,
        SC, SS * SS, SS, SS, DD, 1, DD, 0, nullptr, nullptr, nullptr, 0, nullptr, 0);
    // 5. P (bf16) = softmax(scores), sq
    k_softmax_sq<<<BB * SS, 512, 0, stream>>>(SC, PB, SQ);
    // 6. pdist gram partials ns4 (triangular skip; 576 working blocks, 1 kt)
    mmfa<<<dim3(8, 8, 4 * BB), 256, 0, stream>>>(PB, nullptr, SS, SS * SS, PB, nullptr, SS, SS * SS, 1, 3,
        PDP, 0, SS, SS, SS, 4, 128, 5, nullptr, nullptr, nullptr, 0, nullptr, 0);
    // 7. Bm = sqrt epilogue + symmetric fill
    kbm<<<dim3(256, BB), 256, 0, stream>>>(PDP, SQ, BM);
    // 8. dh
    k_dh<<<BB * SS, 512, 0, stream>>>(BM, DH);
    // 9-10. PW = P @ Wg^T   ns4 + reduce EP0
    mmfa<<<dim3(8, 2, 4 * BB), 256, 0, stream>>>(PB, nullptr, SS, SS * SS, Wg, nullptr, SS, 0, 1, 1,
        PWP, 0, SS, DD, SS, 4, 128, 0, nullptr, nullptr, nullptr, 0, nullptr, 0);
    k_reduce<<<dim3(50, BB), 256, 0, stream>>>(PWP, 4, PW, SS * DD, SS, DD, 0, nullptr, nullptr, nullptr, 0);
    // 11-12. T1s = diag(dh) @ (Bm @ PW)  ns4 + reduce EP2
    mmfa<<<dim3(8, 2, 4 * BB), 256, 0, stream>>>(BM, nullptr, SS, SS * SS, PW, nullptr, DD, SS * DD, 0, 0,
        T1P, 0, SS, DD, SS, 4, 128, 0, nullptr, nullptr, nullptr, 0, nullptr, 0);
    k_reduce<<<dim3(50, BB), 256, 0, stream>>>(T1P, 4, T1, SS * DD, SS, DD, 2, nullptr, nullptr, DH, SS);
    // 13-14. gx = relu(diag(dh) @ (Bm @ T1s) + bg)  ns4 + reduce EP3
    mmfa<<<dim3(8, 2, 4 * BB), 256, 0, stream>>>(BM, nullptr, SS, SS * SS, T1, nullptr, DD, SS * DD, 0, 0,
        GXP, 0, SS, DD, SS, 4, 128, 0, nullptr, nullptr, nullptr, 0, nullptr, 0);
    k_reduce<<<dim3(50, BB), 256, 0, stream>>>(GXP, 4, GX, SS * DD, SS, DD, 3, bg, nullptr, DH, SS);
    // 15. h1 = x @ W4a[:, :100]^T
    mmfa<<<dim3(7, 2, BB), 256, 0, stream>>>(x, nullptr, DD, NN * DD, W4a, nullptr, 2 * DD, 0, 1, 0,
        H1, NN * DD, NN, DD, DD, 1, DD, 0, nullptr, nullptr, nullptr, 0, nullptr, 0);
    // 16. h2 = gx @ W4a[:, 100:]^T
    mmfa<<<dim3(8, 2, BB), 256, 0, stream>>>(GX, nullptr, DD, SS * DD, W4a + DD, nullptr, 2 * DD, 0, 1, 0,
        H2, SS * DD, SS, DD, DD, 1, DD, 0, nullptr, nullptr, nullptr, 0, nullptr, 0);
    // 17. div (b,n,s)
    k_div8<<<dim3(SS / 8, BB), 256, 0, stream>>>(H1, H2, b4a, a4a, W4b, b4b, a4b, DV);
    // 18-19. tmp = div @ gx   ns4 + reduce EP0
    mmfa<<<dim3(7, 2, 4 * BB), 256, 0, stream>>>(DV, nullptr, SS, NN * SS, GX, nullptr, DD, SS * DD, 0, 0,
        TMPP, 0, NN, DD, SS, 4, 128, 0, nullptr, nullptr, nullptr, 0, nullptr, 0);
    k_reduce<<<dim3(40, BB), 256, 0, stream>>>(TMPP, 4, TMP, NN * DD, NN, DD, 0, nullptr, nullptr, nullptr, 0);
    // 20. out = prelu(tmp @ W5^T + b5, a5) + x
    mmfa<<<dim3(7, 2, BB), 256, 0, stream>>>(TMP, nullptr, DD, NN * DD, W5, nullptr, DD, 0, 1, 0,
        out, NN * DD, NN, DD, DD, 1, DD, 4, b5, a5, nullptr, 0, x, NN * DD);
}

// Round 14
// 268.101 us; speedup vs baseline: 2.1560x; 1.0315x over previous
//
#include <hip/hip_runtime.h>
#include <hip/hip_bf16.h>

#define BB 4
#define NN 400
#define DD 100
#define SS 512
#define LPAD 136
#define SMEM_BYTES (64 * LPAD * 2 * 2)

typedef __attribute__((ext_vector_type(8))) short bf16x8;
typedef __attribute__((ext_vector_type(4))) float f32x4;

__device__ __forceinline__ float prelu_f(float v, float a) { return v >= 0.f ? v : a * v; }

__device__ __forceinline__ unsigned short f2bf(float x) {
    union { __hip_bfloat16 h; unsigned short u; } c;
    c.h = __float2bfloat16(x);   // RNE
    return c.u;
}
__device__ __forceinline__ float bf2f(unsigned short u) {
    return __uint_as_float(((unsigned)u) << 16);
}

__device__ __forceinline__ bf16x8 ldfrag(const unsigned short* rowp, int grp) {
    ushort4 lo = *(const ushort4*)(rowp + grp * 4);
    ushort4 hi = *(const ushort4*)(rowp + grp * 4 + 16);
    bf16x8 r = {(short)lo.x, (short)lo.y, (short)lo.z, (short)lo.w,
                (short)hi.x, (short)hi.y, (short)hi.z, (short)hi.w};
    return r;
}

// =====================================================================
// mm_dev: one 64x64 tile over K range [kbeg,kend), bf16 MFMA (verified
// fragment scheme).  aBf/bBf: operand bf16.  A2p/B2p: second fp32 ptr
// summed at staging.  bscale: per-k row scale on B (transB=0 fp32 only).
// EP: 0 plain | 1 prelu(v+bias[n],*al) | 2 v*rv[i] | 3 relu(rv[i]*v+bias[n])
// | 4 prelu(v+bias[n],*al)+res | 5 pdist+mirror.
// =====================================================================
__device__ __forceinline__ void mm_dev(char* smemraw,
    const void* Ap, const void* A2p, int aBf, int lda,
    const void* Bp, const void* B2p, int bBf, int ldb, int transB,
    const float* bscale,
    int i0, int n0, int M, int N, int kbeg, int kend,
    float* C, int ldc, int EP,
    const float* bias, const float* alphaP, const float* rv,
    const float* res, int resLd)
{
    unsigned short (*sa)[LPAD] = (unsigned short(*)[LPAD])smemraw;
    unsigned short (*sb)[LPAD] = (unsigned short(*)[LPAD])(smemraw + 64 * LPAD * 2);
    int tid = threadIdx.x;
    int lane = tid & 63, wave = tid >> 6;
    int r16 = lane & 15, grp = (lane >> 4) & 3;
    int wr = wave >> 1, wc = wave & 1;

    f32x4 acc[2][2];
#pragma unroll
    for (int fm = 0; fm < 2; ++fm)
#pragma unroll
        for (int fn = 0; fn < 2; ++fn)
            acc[fm][fn] = (f32x4){0.f, 0.f, 0.f, 0.f};

    for (int kt = kbeg; kt < kend; kt += 128) {
        // ---- stage A (64 rows x 128 k)
        if (aBf) {
            const unsigned short* Ab = (const unsigned short*)Ap;
#pragma unroll
            for (int it = 0; it < 8; ++it) {
                int idx = tid + it * 256;
                int row = idx >> 5, kq = (idx & 31) * 4;
                ushort4 u = {0, 0, 0, 0};
                if (i0 + row < M && kt + kq + 4 <= kend)
                    u = *(const ushort4*)&Ab[(size_t)(i0 + row) * lda + kt + kq];
                *(ushort4*)&sa[row][kq] = u;
            }
        } else {
            const float* Ab  = (const float*)Ap;
            const float* Ab2 = (const float*)A2p;
#pragma unroll
            for (int it = 0; it < 8; ++it) {
                int idx = tid + it * 256;
                int row = idx >> 5, kq = (idx & 31) * 4;
                float4 v = make_float4(0.f, 0.f, 0.f, 0.f);
                if (i0 + row < M && kt + kq + 4 <= kend) {
                    v = *(const float4*)&Ab[(size_t)(i0 + row) * lda + kt + kq];
                    if (Ab2) {
                        float4 w = *(const float4*)&Ab2[(size_t)(i0 + row) * lda + kt + kq];
                        v.x += w.x; v.y += w.y; v.z += w.z; v.w += w.w;
                    }
                }
                ushort4 u;
                u.x = f2bf(v.x); u.y = f2bf(v.y); u.z = f2bf(v.z); u.w = f2bf(v.w);
                *(ushort4*)&sa[row][kq] = u;
            }
        }
        // ---- stage B
        if (transB) {
            if (bBf) {
                const unsigned short* Bb = (const unsigned short*)Bp;
#pragma unroll
                for (int it = 0; it < 8; ++it) {
                    int idx = tid + it * 256;
                    int row = idx >> 5, kq = (idx & 31) * 4;
                    ushort4 u = {0, 0, 0, 0};
                    if (n0 + row < N && kt + kq + 4 <= kend)
                        u = *(const ushort4*)&Bb[(size_t)(n0 + row) * ldb + kt + kq];
                    *(ushort4*)&sb[row][kq] = u;
                }
            } else {
                const float* Bb  = (const float*)Bp;
                const float* Bb2 = (const float*)B2p;
#pragma unroll
                for (int it = 0; it < 8; ++it) {
                    int idx = tid + it * 256;
                    int row = idx >> 5, kq = (idx & 31) * 4;
                    float4 v = make_float4(0.f, 0.f, 0.f, 0.f);
                    if (n0 + row < N && kt + kq + 4 <= kend) {
                        v = *(const float4*)&Bb[(size_t)(n0 + row) * ldb + kt + kq];
                        if (Bb2) {
                            float4 w = *(const float4*)&Bb2[(size_t)(n0 + row) * ldb + kt + kq];
                            v.x += w.x; v.y += w.y; v.z += w.z; v.w += w.w;
                        }
                    }
                    ushort4 u;
                    u.x = f2bf(v.x); u.y = f2bf(v.y); u.z = f2bf(v.z); u.w = f2bf(v.w);
                    *(ushort4*)&sb[row][kq] = u;
                }
            }
        } else {
            const float* Bb  = (const float*)Bp;
            const float* Bb2 = (const float*)B2p;
#pragma unroll
            for (int it = 0; it < 8; ++it) {
                int idx = tid + it * 256;
                int kk = idx >> 4;           // 0..127
                int nq = (idx & 15) * 4;     // 0..60
                float4 v = make_float4(0.f, 0.f, 0.f, 0.f);
                if (kt + kk < kend && n0 + nq + 4 <= N) {
                    v = *(const float4*)&Bb[(size_t)(kt + kk) * ldb + n0 + nq];
                    if (Bb2) {
                        float4 w = *(const float4*)&Bb2[(size_t)(kt + kk) * ldb + n0 + nq];
                        v.x += w.x; v.y += w.y; v.z += w.z; v.w += w.w;
                    }
                    if (bscale) {
                        float s = bscale[kt + kk];
                        v.x *= s; v.y *= s; v.z *= s; v.w *= s;
                    }
                }
                sb[nq + 0][kk] = f2bf(v.x);
                sb[nq + 1][kk] = f2bf(v.y);
                sb[nq + 2][kk] = f2bf(v.z);
                sb[nq + 3][kk] = f2bf(v.w);
            }
        }
        __syncthreads();

#pragma unroll
        for (int ks = 0; ks < 4; ++ks) {
            bf16x8 a0 = ldfrag(&sa[wr * 32 + r16][ks * 32], grp);
            bf16x8 a1 = ldfrag(&sa[wr * 32 + 16 + r16][ks * 32], grp);
            bf16x8 b0 = ldfrag(&sb[wc * 32 + r16][ks * 32], grp);
            bf16x8 b1 = ldfrag(&sb[wc * 32 + 16 + r16][ks * 32], grp);
            acc[0][0] = __builtin_amdgcn_mfma_f32_16x16x32_bf16(a0, b0, acc[0][0], 0, 0, 0);
            acc[0][1] = __builtin_amdgcn_mfma_f32_16x16x32_bf16(a0, b1, acc[0][1], 0, 0, 0);
            acc[1][0] = __builtin_amdgcn_mfma_f32_16x16x32_bf16(a1, b0, acc[1][0], 0, 0, 0);
            acc[1][1] = __builtin_amdgcn_mfma_f32_16x16x32_bf16(a1, b1, acc[1][1], 0, 0, 0);
        }
        __syncthreads();
    }

    float al = alphaP ? *alphaP : 0.f;
#pragma unroll
    for (int fm = 0; fm < 2; ++fm)
#pragma unroll
        for (int fn = 0; fn < 2; ++fn)
#pragma unroll
            for (int reg = 0; reg < 4; ++reg) {
                int i = i0 + wr * 32 + fm * 16 + grp * 4 + reg;
                int n = n0 + wc * 32 + fn * 16 + r16;
                if (i >= M || n >= N) continue;
                float v = acc[fm][fn][reg];
                if (EP == 1) v = prelu_f(v + bias[n], al);
                else if (EP == 2) v *= rv[i];
                else if (EP == 3) { float t = rv[i] * v + bias[n]; v = t > 0.f ? t : 0.f; }
                else if (EP == 4) v = prelu_f(v + bias[n], al) + res[(size_t)i * resLd + n];
                else if (EP == 5) {
                    float d2 = rv[i] + rv[n] - 2.f * v;
                    v = (i == n) ? 1.f : sqrtf(fmaxf(d2, 0.f));
                }
                C[(size_t)i * ldc + n] = v;
                if (EP == 5) C[(size_t)n * ldc + i] = v;
            }
}

// =====================================================================
// Generic batched wrapper (r13 semantics + bscale).
// =====================================================================
__global__ __launch_bounds__(256)
void mmfa(const void* Ap, const void* A2p, int lda, int sA,
          const void* Bp, const void* B2p, int ldb, int sB,
          int transB, int flags,
          const float* bscale, int bscaleStride,
          float* C, int sC, int M, int N, int K,
          int nsplit, int kchunk, int EP,
          const float* bias, const float* alpha,
          const float* rv, int rvStride,
          const float* res, int sRes)
{
    __shared__ __align__(16) char sm[SMEM_BYTES];
    int zz = blockIdx.z;
    int b = zz / nsplit, split = zz - b * nsplit;
    int kbeg = split * kchunk, kend = min(K, kbeg + kchunk);
    int i0 = blockIdx.x * 64, n0 = blockIdx.y * 64;
    if (EP == 5 && i0 > n0) return;

    const void* Ab; const void* Ab2 = nullptr;
    if (flags & 1) Ab = (const void*)((const unsigned short*)Ap + (size_t)b * sA);
    else {
        Ab = (const void*)((const float*)Ap + (size_t)b * sA);
        if (A2p) Ab2 = (const void*)((const float*)A2p + (size_t)b * sA);
    }
    const void* Bb; const void* Bb2 = nullptr;
    if (flags & 2) Bb = (const void*)((const unsigned short*)Bp + (size_t)b * sB);
    else {
        Bb = (const void*)((const float*)Bp + (size_t)b * sB);
        if (B2p) Bb2 = (const void*)((const float*)B2p + (size_t)b * sB);
    }
    const float* bs = bscale ? bscale + (size_t)b * bscaleStride : nullptr;

    float* Cd; int ep;
    if (nsplit > 1) { Cd = C + (size_t)(b * nsplit + split) * M * N; ep = 0; }
    else            { Cd = C + (size_t)b * sC; ep = EP; }
    const float* rvb = rv ? rv + (size_t)b * rvStride : nullptr;
    const float* resb = res ? res + (size_t)b * sRes : nullptr;

    mm_dev(sm, Ab, Ab2, flags & 1, lda, Bb, Bb2, flags & 2, ldb, transB, bs,
           i0, n0, M, N, kbeg, kend, Cd, N, ep, bias, alpha, rvb, resb, N);
}

// =====================================================================
// preU: union of independent GEMM partial tiles.
//  t<64   : G1P ns4 (G @ Wgf^T), 1kt each
//  t<192  : AXP ns2 (Am @ x[b]), 2kt each
//  else 56: H1  (x[b] @ W4a[:,:100]^T), 1kt
// =====================================================================
__global__ __launch_bounds__(256)
void preU(const float* G, const float* Wgf, const float* Am, const float* x,
          const float* W4a, float* G1P, float* AXP, float* H1)
{
    __shared__ __align__(16) char sm[SMEM_BYTES];
    int t = blockIdx.x;
    if (t < 64) {
        int split = t >> 4, rem = t & 15, ix = rem >> 1, iy = rem & 1;
        mm_dev(sm, G, nullptr, 0, NN, Wgf, nullptr, 0, NN, 1, nullptr,
               ix * 64, iy * 64, SS, DD, split * 100, split * 100 + 100,
               G1P + (size_t)split * SS * DD, DD, 0,
               nullptr, nullptr, nullptr, nullptr, 0);
    } else if (t < 192) {
        int u = t - 64;
        int b = u >> 5, rem = u & 31, split = rem >> 4, r2 = rem & 15;
        int ix = r2 >> 1, iy = r2 & 1;
        mm_dev(sm, Am, nullptr, 0, NN, x + (size_t)b * NN * DD, nullptr, 0, DD, 0, nullptr,
               ix * 64, iy * 64, SS, DD, split * 200, split * 200 + 200,
               AXP + (size_t)(b * 2 + split) * SS * DD, DD, 0,
               nullptr, nullptr, nullptr, nullptr, 0);
    } else {
        int u = t - 192;
        int b = u / 14, rem = u % 14, ix = rem >> 1, iy = rem & 1;
        mm_dev(sm, x + (size_t)b * NN * DD, nullptr, 0, DD, W4a, nullptr, 0, 2 * DD, 1, nullptr,
               ix * 64, iy * 64, NN, DD, 0, DD,
               H1 + (size_t)b * NN * DD, DD, 0,
               nullptr, nullptr, nullptr, nullptr, 0);
    }
}

// =====================================================================
// gramU: pdist gram partials (t<1024, triangular, ns4 1kt) union
// PW partials (128, ns2 2kt).  Both read only PB.
// =====================================================================
__global__ __launch_bounds__(256)
void gramU(const unsigned short* PB, const float* Wg, float* PDP, float* PWP)
{
    __shared__ __align__(16) char sm[SMEM_BYTES];
    int t = blockIdx.x;
    if (t < 1024) {
        int z = t >> 6, rem = t & 63, ix = rem >> 3, iy = rem & 7;
        if (ix > iy) return;
        int b = z >> 2, split = z & 3;
        const unsigned short* Pbb = PB + (size_t)b * SS * SS;
        mm_dev(sm, Pbb, nullptr, 1, SS, Pbb, nullptr, 1, SS, 1, nullptr,
               ix * 64, iy * 64, SS, SS, split * 128, split * 128 + 128,
               PDP + (size_t)(b * 4 + split) * SS * SS, SS, 0,
               nullptr, nullptr, nullptr, nullptr, 0);
    } else {
        int u = t - 1024;
        int z = u >> 4, rem = u & 15, ix = rem >> 1, iy = rem & 1;
        int b = z >> 1, split = z & 1;
        mm_dev(sm, PB + (size_t)b * SS * SS, nullptr, 1, SS, Wg, nullptr, 0, SS, 1, nullptr,
               ix * 64, iy * 64, SS, DD, split * 256, split * 256 + 256,
               PWP + (size_t)(b * 2 + split) * SS * DD, DD, 0,
               nullptr, nullptr, nullptr, nullptr, 0);
    }
}

// =====================================================================
// kbm2: pdist epilogue over 4 gram partials (upper-tri at [lo][hi]) +
// fused dh.  Block covers exactly 2 full rows (1024 elems).
// =====================================================================
__global__ __launch_bounds__(256)
void kbm2(const float* __restrict__ parts, const float* __restrict__ sq,
          float* __restrict__ Bm, float* __restrict__ dh)
{
    __shared__ float red[4];
    int b = blockIdx.y;
    int tid = threadIdx.x;
    int flat = (blockIdx.x * 256 + tid) * 4;
    int i = flat / SS, n0 = flat - i * SS;
    const float* pb = parts + (size_t)b * 4 * SS * SS;
    const float* sqb = sq + (size_t)b * SS;
    float o[4];
#pragma unroll
    for (int j = 0; j < 4; ++j) {
        int n = n0 + j;
        int lo = min(i, n), hi = max(i, n);
        size_t idx = (size_t)lo * SS + hi;
        float d = pb[idx] + pb[(size_t)SS * SS + idx]
                + pb[2 * (size_t)SS * SS + idx] + pb[3 * (size_t)SS * SS + idx];
        float d2 = sqb[i] + sqb[n] - 2.f * d;
        o[j] = (i == n) ? 1.f : sqrtf(fmaxf(d2, 0.f));
    }
    *(float4*)&Bm[(size_t)b * SS * SS + flat] = make_float4(o[0], o[1], o[2], o[3]);

    float rs = o[0] + o[1] + o[2] + o[3];
    for (int off = 32; off; off >>= 1) rs += __shfl_xor(rs, off, 64);
    int lane = tid & 63, wave = tid >> 6;
    if (lane == 0) red[wave] = rs;
    __syncthreads();
    if (tid == 0)   dh[(size_t)b * SS + blockIdx.x * 2]     = rsqrtf(red[0] + red[1]);
    if (tid == 128) dh[(size_t)b * SS + blockIdx.x * 2 + 1] = rsqrtf(red[2] + red[3]);
}

// =====================================================================
// Split-K reduce with epilogue (G1 only now).
// =====================================================================
__global__ __launch_bounds__(256)
void k_reduce(const float* __restrict__ part, int nsplit, float* __restrict__ C, int sC,
              int M, int N, int EP, const float* __restrict__ bias,
              const float* __restrict__ alpha, const float* __restrict__ rv, int rvStride)
{
    int b = blockIdx.y;
    int MN = M * N;
    int flat = (blockIdx.x * 256 + threadIdx.x) * 4;
    if (flat >= MN) return;
    const float* p = part + (size_t)b * nsplit * MN + flat;
    float4 v = *(const float4*)p;
    for (int s = 1; s < nsplit; ++s) {
        float4 w = *(const float4*)(p + (size_t)s * MN);
        v.x += w.x; v.y += w.y; v.z += w.z; v.w += w.w;
    }
    float o[4] = {v.x, v.y, v.z, v.w};
    int i = flat / N, n = flat - i * N;
    if (EP == 1) {
        float al = *alpha;
#pragma unroll
        for (int j = 0; j < 4; ++j) o[j] = prelu_f(o[j] + bias[n + j], al);
    } else if (EP == 2) {
        float r = rv[(size_t)b * rvStride + i];
#pragma unroll
        for (int j = 0; j < 4; ++j) o[j] *= r;
    } else if (EP == 3) {
        float r = rv[(size_t)b * rvStride + i];
#pragma unroll
        for (int j = 0; j < 4; ++j) { float t = r * o[j] + bias[n + j]; o[j] = t > 0.f ? t : 0.f; }
    }
    float* co = C + (size_t)b * sC + flat;
    *(float4*)co = make_float4(o[0], o[1], o[2], o[3]);
}

// =====================================================================
// Row softmax over 512 cols -> P bf16, sq = sum(bf16(p)^2).
// =====================================================================
__global__ __launch_bounds__(512)
void k_softmax_sq(const float* __restrict__ scores, unsigned short* __restrict__ Pb,
                  float* __restrict__ sq)
{
    int row = blockIdx.x;
    int t = threadIdx.x;
    int w = t >> 6, lane = t & 63;
    __shared__ float sm[8];

    float v = scores[(size_t)row * SS + t];
    float m = v;
    for (int off = 32; off; off >>= 1) m = fmaxf(m, __shfl_xor(m, off, 64));
    if (lane == 0) sm[w] = m;
    __syncthreads();
    m = sm[0];
#pragma unroll
    for (int i = 1; i < 8; ++i) m = fmaxf(m, sm[i]);
    __syncthreads();

    float e = expf(v - m);
    float s = e;
    for (int off = 32; off; off >>= 1) s += __shfl_xor(s, off, 64);
    if (lane == 0) sm[w] = s;
    __syncthreads();
    s = 0.f;
#pragma unroll
    for (int i = 0; i < 8; ++i) s += sm[i];
    __syncthreads();

    unsigned short u = f2bf(e / s);
    Pb[(size_t)row * SS + t] = u;
    float pf = bf2f(u);
    float q = pf * pf;
    for (int off = 32; off; off >>= 1) q += __shfl_xor(q, off, 64);
    if (lane == 0) sm[w] = q;
    __syncthreads();
    if (t == 0) {
        float r = 0.f;
#pragma unroll
        for (int i = 0; i < 8; ++i) r += sm[i];
        sq[row] = r;
    }
}

// =====================================================================
// Logits + softmax over n.  block = (b, 8 s-rows), 256 thr.
// =====================================================================
__global__ __launch_bounds__(256)
void k_div8(const float* __restrict__ h1, const float* __restrict__ h2,
            const float* __restrict__ b4a, const float* __restrict__ a4ap,
            const float* __restrict__ W4b, const float* __restrict__ b4bp,
            const float* __restrict__ a4bp, float* __restrict__ divT)
{
    int b = blockIdx.y;
    int s0 = blockIdx.x * 8;
    int tid = threadIdx.x;

    __shared__ float sh[8][104];
    __shared__ float sw[100];
    __shared__ float L[8][400];

    for (int idx = tid; idx < 800; idx += 256) {
        int s = idx / 100, d = idx - 100 * s;
        sh[s][d] = h2[((size_t)(b * SS + s0 + s)) * DD + d] + b4a[d];
    }
    if (tid < 100) sw[tid] = W4b[tid];
    __syncthreads();

    float a4a = *a4ap, a4b = *a4bp, b4b = *b4bp;

    for (int n = tid; n < NN; n += 256) {
        const float* h1r = &h1[((size_t)b * NN + n) * DD];
        float accs[8] = {0.f, 0.f, 0.f, 0.f, 0.f, 0.f, 0.f, 0.f};
        for (int j = 0; j < DD; j += 4) {
            float4 hv = *(const float4*)&h1r[j];
            float4 wv = *(const float4*)&sw[j];
#pragma unroll
            for (int s = 0; s < 8; ++s) {
                float4 cv = *(const float4*)&sh[s][j];
                float x0 = hv.x + cv.x; x0 = x0 > 0.f ? x0 : a4a * x0;
                float x1 = hv.y + cv.y; x1 = x1 > 0.f ? x1 : a4a * x1;
                float x2 = hv.z + cv.z; x2 = x2 > 0.f ? x2 : a4a * x2;
                float x3 = hv.w + cv.w; x3 = x3 > 0.f ? x3 : a4a * x3;
                accs[s] += x0 * wv.x + x1 * wv.y + x2 * wv.z + x3 * wv.w;
            }
        }
#pragma unroll
        for (int s = 0; s < 8; ++s) L[s][n] = prelu_f(accs[s] + b4b, a4b);
    }
    __syncthreads();

    int w = tid >> 6, lane = tid & 63;
    for (int si = w; si < 8; si += 4) {
        float m = -INFINITY;
        for (int n = lane; n < NN; n += 64) m = fmaxf(m, L[si][n]);
        for (int off = 32; off; off >>= 1) m = fmaxf(m, __shfl_xor(m, off, 64));
        float ss = 0.f;
        for (int n = lane; n < NN; n += 64) {
            float e = expf(L[si][n] - m);
            L[si][n] = e;
            ss += e;
        }
        for (int off = 32; off; off >>= 1) ss += __shfl_xor(ss, off, 64);
        float inv = 1.f / ss;
        for (int n = lane; n < NN; n += 64)
            divT[((size_t)b * NN + n) * SS + s0 + si] = L[si][n] * inv;
    }
}

extern "C" void kernel_launch(void* const* d_in, const int* in_sizes, int n_in,
                              void* d_out, int out_size, void* d_ws, size_t ws_size,
                              hipStream_t stream) {
    const float* x   = (const float*)d_in[0];
    const float* G   = (const float*)d_in[1];
    const float* Am  = (const float*)d_in[2];
    const float* Wgf = (const float*)d_in[3];
    const float* bgf = (const float*)d_in[4];
    const float* agf = (const float*)d_in[5];
    const float* Wg  = (const float*)d_in[6];
    const float* bg  = (const float*)d_in[7];
    const float* W4a = (const float*)d_in[8];
    const float* b4a = (const float*)d_in[9];
    const float* a4a = (const float*)d_in[10];
    const float* W4b = (const float*)d_in[11];
    const float* b4b = (const float*)d_in[12];
    const float* a4b = (const float*)d_in[13];
    const float* W5  = (const float*)d_in[14];
    const float* b5  = (const float*)d_in[15];
    const float* a5  = (const float*)d_in[16];
    float* out = (float*)d_out;

    float* ws = (float*)d_ws;
    float* G1   = ws + 0;         // 51200
    float* G1P  = ws + 51200;     // 204800
    float* AXP  = ws + 256000;    // 409600
    float* SC   = ws + 665600;    // 1048576
    float* BM   = ws + 1714176;   // 1048576
    float* SQ   = ws + 2762752;   // 2048
    float* DH   = ws + 2764800;   // 2048
    float* PDP  = ws + 2766848;   // 4194304
    float* PWP  = ws + 6961152;   // 409600
    float* T1P  = ws + 7370752;   // 409600
    float* GX   = ws + 7780352;   // 204800
    float* H1   = ws + 7985152;   // 160000
    float* H2   = ws + 8145152;   // 204800
    float* DV   = ws + 8349952;   // 819200
    float* TMPP = ws + 9169152;   // 320000
    unsigned short* PB = (unsigned short*)(ws + 9489152);  // 1048576 ushorts

    // 1. preU: G1 partials + Ax partials + h1                 [248 blocks]
    preU<<<248, 256, 0, stream>>>(G, Wgf, Am, x, W4a, G1P, AXP, H1);
    // 2. G1 = prelu(sum4 + bgf)
    k_reduce<<<dim3(50, 1), 256, 0, stream>>>(G1P, 4, G1, SS * DD, SS, DD, 1, bgf, agf, nullptr, 0);
    // 3. scores = G1 @ (Ax0+Ax1)^T                            [256 blocks]
    mmfa<<<dim3(8, 8, BB), 256, 0, stream>>>(G1, nullptr, DD, 0,
        AXP, AXP + SS * DD, DD, 2 * SS * DD, 1, 0, nullptr, 0,
        SC, SS * SS, SS, SS, DD, 1, DD, 0, nullptr, nullptr, nullptr, 0, nullptr, 0);
    // 4. P (bf16) = softmax(scores), sq
    k_softmax_sq<<<BB * SS, 512, 0, stream>>>(SC, PB, SQ);
    // 5. gramU: pdist gram partials (tri) + PW partials       [1152 blocks]
    gramU<<<1152, 256, 0, stream>>>(PB, Wg, PDP, PWP);
    // 6. kbm2: Bm (sqrt + symmetric fill) + dh fused
    kbm2<<<dim3(256, BB), 256, 0, stream>>>(PDP, SQ, BM, DH);
    // 7. T1 partials = Bm @ (PW0+PW1)   ns2
    mmfa<<<dim3(8, 2, 2 * BB), 256, 0, stream>>>(BM, nullptr, SS, SS * SS,
        PWP, PWP + SS * DD, DD, 2 * SS * DD, 0, 0, nullptr, 0,
        T1P, 0, SS, DD, SS, 2, 256, 0, nullptr, nullptr, nullptr, 0, nullptr, 0);
    // 8. gx = relu(dh_i * (Bm @ (dh_k*(T10+T11))) + bg)   ns1 K=512, EP3
    mmfa<<<dim3(8, 2, BB), 256, 0, stream>>>(BM, nullptr, SS, SS * SS,
        T1P, T1P + SS * DD, DD, 2 * SS * DD, 0, 0, DH, SS,
        GX, SS * DD, SS, DD, SS, 1, SS, 3, bg, nullptr, DH, SS, nullptr, 0);
    // 9. h2 = gx @ W4a[:, 100:]^T
    mmfa<<<dim3(8, 2, BB), 256, 0, stream>>>(GX, nullptr, DD, SS * DD,
        W4a + DD, nullptr, 2 * DD, 0, 1, 0, nullptr, 0,
        H2, SS * DD, SS, DD, DD, 1, DD, 0, nullptr, nullptr, nullptr, 0, nullptr, 0);
    // 10. div (b,n,s)
    k_div8<<<dim3(SS / 8, BB), 256, 0, stream>>>(H1, H2, b4a, a4a, W4b, b4b, a4b, DV);
    // 11. tmp partials = div @ gx   ns2
    mmfa<<<dim3(7, 2, 2 * BB), 256, 0, stream>>>(DV, nullptr, SS, NN * SS,
        GX, nullptr, DD, SS * DD, 0, 0, nullptr, 0,
        TMPP, 0, NN, DD, SS, 2, 256, 0, nullptr, nullptr, nullptr, 0, nullptr, 0);
    // 12. out = prelu((tmp0+tmp1) @ W5^T + b5, a5) + x
    mmfa<<<dim3(7, 2, BB), 256, 0, stream>>>(TMPP, TMPP + NN * DD, DD, 2 * NN * DD,
        W5, nullptr, DD, 0, 1, 0, nullptr, 0,
        out, NN * DD, NN, DD, DD, 1, DD, 4, b5, a5, nullptr, 0, x, NN * DD);
}